// Round 5
// baseline (577.676 us; speedup 1.0000x reference)
//
#include <hip/hip_runtime.h>

typedef unsigned int uint;
typedef unsigned short ushort;
typedef unsigned long long ull;

#define F_IN 64
#define HD 32
#define NCLS 2
#define BN_EPS 1e-5f
#define SCHUNK 1024
#define NPW 8
#define FIX_SCALE 1073741824.0f            // 2^30
#define FIX_INV   9.313225746154785e-10f   // 2^-30
#define MASK40 ((1ULL << 40) - 1)

__device__ __forceinline__ ushort f2bf(float f) {
    uint u = __float_as_uint(f);
    u = (u + 0x7FFFu + ((u >> 16) & 1u)) >> 16;   // RNE
    return (ushort)u;
}
__device__ __forceinline__ float bf_lo(uint w) { return __uint_as_float(w << 16); }
__device__ __forceinline__ float bf_hi(uint w) { return __uint_as_float(w & 0xFFFF0000u); }
__device__ __forceinline__ ull nt_ld64(const int2* p) {
    return __builtin_nontemporal_load(reinterpret_cast<const ull*>(p));
}

// ---------- fused histogram: u64 atomic = count(hi24)+fixedpoint deg(lo40); epos = rank ----------
__global__ void hist64_kernel(const int* __restrict__ ei, const float* __restrict__ w,
                              ull* __restrict__ packed, ushort* __restrict__ epos, int E) {
    int e = blockIdx.x * blockDim.x + threadIdx.x;
    if (e >= E) return;
    int c = __builtin_nontemporal_load(ei + E + e);
    float we = __builtin_nontemporal_load(w + e);
    ull fx = (ull)(we * FIX_SCALE + 0.5f);
    ull old = atomicAdd(&packed[c], (1ULL << 40) | fx);
    __builtin_nontemporal_store((ushort)(old >> 40), epos + e);
}

// ---------- scan phase A: per-chunk counts-sums; fused dis = rsqrt(deg+1) ----------
__global__ void scanA_kernel(const ull* __restrict__ packed,
                             int* __restrict__ partial, float* __restrict__ dis, int n) {
    __shared__ int red[256];
    int base = blockIdx.x * SCHUNK;
    int tid = threadIdx.x;
    int s = 0;
    for (int i = tid; i < SCHUNK; i += 256) {
        int idx = base + i;
        if (idx < n) {
            ull p = packed[idx];
            s += (int)(p >> 40);
            float deg = (float)(p & MASK40) * FIX_INV;
            dis[idx] = rsqrtf(deg + 1.0f);   // self-loop weight 1; arg >= 1
        }
    }
    red[tid] = s;
    __syncthreads();
    for (int off = 128; off > 0; off >>= 1) {
        if (tid < off) red[tid] += red[tid + off];
        __syncthreads();
    }
    if (tid == 0) partial[blockIdx.x] = red[0];
}

// ---------- scan phase B ----------
__global__ void scanB_kernel(int* __restrict__ partial, int nb, int* __restrict__ offs_n) {
    __shared__ int lds[256];
    int tid = threadIdx.x;
    int v = (tid < nb) ? partial[tid] : 0;
    lds[tid] = v;
    __syncthreads();
    for (int off = 1; off < 256; off <<= 1) {
        int t = (tid >= off) ? lds[tid - off] : 0;
        __syncthreads();
        lds[tid] += t;
        __syncthreads();
    }
    if (tid < nb) partial[tid] = lds[tid] - v;
    if (tid == nb - 1) *offs_n = lds[tid];
}

// ---------- scan phase C ----------
__global__ void scanC_kernel(const ull* __restrict__ packed, const int* __restrict__ partial,
                             int* __restrict__ offs, int n) {
    __shared__ int lds[256];
    int tid = threadIdx.x;
    int i0 = blockIdx.x * SCHUNK + tid * 4;
    int c0 = 0, c1 = 0, c2 = 0, c3 = 0;
    if (i0 + 0 < n) c0 = (int)(packed[i0 + 0] >> 40);
    if (i0 + 1 < n) c1 = (int)(packed[i0 + 1] >> 40);
    if (i0 + 2 < n) c2 = (int)(packed[i0 + 2] >> 40);
    if (i0 + 3 < n) c3 = (int)(packed[i0 + 3] >> 40);
    int tsum = c0 + c1 + c2 + c3;
    lds[tid] = tsum;
    __syncthreads();
    for (int off = 1; off < 256; off <<= 1) {
        int t = (tid >= off) ? lds[tid - off] : 0;
        __syncthreads();
        lds[tid] += t;
        __syncthreads();
    }
    int run = partial[blockIdx.x] + lds[tid] - tsum;
    int o0 = run, o1 = o0 + c0, o2 = o1 + c1, o3 = o2 + c2;
    if (i0 + 0 < n) offs[i0 + 0] = o0;
    if (i0 + 1 < n) offs[i0 + 1] = o1;
    if (i0 + 2 < n) offs[i0 + 2] = o2;
    if (i0 + 3 < n) offs[i0 + 3] = o3;
}

// ---------- fill CSR (atomic-free): pos = offs[col] + epos[e] ----------
__global__ void fill_kernel(const int* __restrict__ ei, const float* __restrict__ w,
                            const float* __restrict__ dis, const int* __restrict__ offs,
                            const ushort* __restrict__ epos, int2* __restrict__ centry, int E) {
    int e = blockIdx.x * blockDim.x + threadIdx.x;
    if (e >= E) return;
    int r = __builtin_nontemporal_load(ei + e);
    int c = __builtin_nontemporal_load(ei + E + e);
    float we = __builtin_nontemporal_load(w + e);
    float nw = dis[r] * we * dis[c];
    int pos = offs[c] + (int)__builtin_nontemporal_load(epos + e);
    ull pk = (ull)(uint)r | ((ull)(uint)__float_as_int(nw) << 32);
    __builtin_nontemporal_store(pk, reinterpret_cast<ull*>(centry + pos));
}

// ---------- small GEMM: writes fp32 + bf16 tables; BN inline; zeroes statsCur ----------
template <int FIN, bool BN>
__global__ void gemm_kernel(const float* __restrict__ X, const float* __restrict__ W,
                            const float* __restrict__ statsPrev, const float* __restrict__ g,
                            const float* __restrict__ be, float* __restrict__ Hf,
                            ushort* __restrict__ Hb, float* __restrict__ statsCur, int n) {
    __shared__ float Wl[FIN * HD];
    __shared__ float scl[64];
    for (int i = threadIdx.x; i < FIN * HD; i += blockDim.x) Wl[i] = W[i];
    if (BN && threadIdx.x < 32) {
        int h = threadIdx.x;
        float invn = 1.0f / (float)n;
        float mean = statsPrev[h] * invn;
        float var = statsPrev[32 + h] * invn - mean * mean;   // biased
        float sca = rsqrtf(var + BN_EPS) * g[h];
        scl[h] = sca;
        scl[32 + h] = be[h] - mean * sca;
    }
    if (blockIdx.x == 0 && threadIdx.x < 64) statsCur[threadIdx.x] = 0.0f;
    __syncthreads();
    int idx = blockIdx.x * blockDim.x + threadIdx.x;
    if (idx >= n * HD) return;
    int node = idx >> 5, h = idx & 31;
    const float4* xr4 = reinterpret_cast<const float4*>(X + (size_t)node * FIN);
    float acc = 0.0f;
#pragma unroll
    for (int q = 0; q < FIN / 4; q++) {
        float4 v4 = xr4[q];
        float vs[4] = {v4.x, v4.y, v4.z, v4.w};
#pragma unroll
        for (int j = 0; j < 4; j++) {
            int k = q * 4 + j;
            float v = vs[j];
            if (BN) v = v * scl[k] + scl[32 + k];
            acc += v * Wl[k * HD + h];
        }
    }
    Hf[idx] = acc;
    Hb[idx] = f2bf(acc);
}

// ================= agg variant V0: 32-lane fp32 gather, 2 subs, 2-deep =================
__global__ void aggV0_kernel(const float* __restrict__ hf, const int* __restrict__ offs,
                             const int2* __restrict__ centry, const float* __restrict__ dis,
                             const float* __restrict__ bias, float* __restrict__ y,
                             float* __restrict__ stats, int n) {
    int wave = threadIdx.x >> 6, lane = threadIdx.x & 63, sub = lane >> 5, h = lane & 31;
    float bv = bias[h];
    float lsum = 0.f, lsq = 0.f;
    int base = (blockIdx.x * 4 + wave) * NPW;
    for (int t = 0; t < NPW; t++) {
        int node = base + t;
        if (node >= n) break;
        int s = offs[node], e2 = offs[node + 1];
        float acc = 0.f, acc2 = 0.f;
        if (sub == 0) {
            float d = dis[node];
            acc = hf[(size_t)node * HD + h] * d * d;
        }
        int j = s + sub;
        for (; j + 2 < e2; j += 4) {
            ull pa = nt_ld64(centry + j);
            ull pb = nt_ld64(centry + j + 2);
            int ra = (int)(uint)pa, rb = (int)(uint)pb;
            float wa = __uint_as_float((uint)(pa >> 32));
            float wb = __uint_as_float((uint)(pb >> 32));
            acc  += hf[(size_t)ra * HD + h] * wa;
            acc2 += hf[(size_t)rb * HD + h] * wb;
        }
        if (j < e2) {
            ull pa = nt_ld64(centry + j);
            int ra = (int)(uint)pa;
            float wa = __uint_as_float((uint)(pa >> 32));
            acc += hf[(size_t)ra * HD + h] * wa;
        }
        acc += acc2;
        acc += __shfl_xor(acc, 32, 64);
        float yv = fmaxf(acc + bv, 0.f);
        if (sub == 0) {
            y[(size_t)node * HD + h] = yv;
            lsum += yv; lsq += yv * yv;
        }
    }
    __shared__ float ls[4][32], lq[4][32];
    if (sub == 0) { ls[wave][h] = lsum; lq[wave][h] = lsq; }
    __syncthreads();
    if (threadIdx.x < 32) {
        float a = ls[0][threadIdx.x] + ls[1][threadIdx.x] + ls[2][threadIdx.x] + ls[3][threadIdx.x];
        float b = lq[0][threadIdx.x] + lq[1][threadIdx.x] + lq[2][threadIdx.x] + lq[3][threadIdx.x];
        atomicAdd(&stats[threadIdx.x], a);
        atomicAdd(&stats[32 + threadIdx.x], b);
    }
}

// ================= agg variant V1: 16-lane bf16 gather, 4 grps, 2-deep =================
__global__ void aggV1_kernel(const uint* __restrict__ hb, const int* __restrict__ offs,
                             const int2* __restrict__ centry, const float* __restrict__ dis,
                             const float* __restrict__ bias, float* __restrict__ y,
                             float* __restrict__ stats, int n) {
    int wave = threadIdx.x >> 6, lane = threadIdx.x & 63;
    int grp = lane >> 4, l = lane & 15;
    float b0 = bias[2 * l], b1 = bias[2 * l + 1];
    float s0 = 0.f, s1 = 0.f, q0 = 0.f, q1 = 0.f;
    int base = (blockIdx.x * 4 + wave) * NPW;
    for (int t = 0; t < NPW; t++) {
        int node = base + t;
        if (node >= n) break;
        int s = offs[node], e2 = offs[node + 1];
        float a0 = 0.f, a1 = 0.f, c0 = 0.f, c1 = 0.f;
        if (grp == 0) {
            float d = dis[node];
            float dd = d * d;
            uint hv = hb[(size_t)node * 16 + l];
            a0 = bf_lo(hv) * dd;
            a1 = bf_hi(hv) * dd;
        }
        int j = s + grp;
        for (; j + 4 < e2; j += 8) {
            ull pa = nt_ld64(centry + j);
            ull pb = nt_ld64(centry + j + 4);
            uint ha = hb[(size_t)(uint)pa * 16 + l];
            uint hbv = hb[(size_t)(uint)pb * 16 + l];
            float wa = __uint_as_float((uint)(pa >> 32));
            float wb = __uint_as_float((uint)(pb >> 32));
            a0 += bf_lo(ha) * wa; a1 += bf_hi(ha) * wa;
            c0 += bf_lo(hbv) * wb; c1 += bf_hi(hbv) * wb;
        }
        if (j < e2) {
            ull pa = nt_ld64(centry + j);
            uint ha = hb[(size_t)(uint)pa * 16 + l];
            float wa = __uint_as_float((uint)(pa >> 32));
            a0 += bf_lo(ha) * wa; a1 += bf_hi(ha) * wa;
        }
        a0 += c0; a1 += c1;
        a0 += __shfl_xor(a0, 16, 64); a1 += __shfl_xor(a1, 16, 64);
        a0 += __shfl_xor(a0, 32, 64); a1 += __shfl_xor(a1, 32, 64);
        float y0 = fmaxf(a0 + b0, 0.f), y1 = fmaxf(a1 + b1, 0.f);
        if (grp == 0) {
            *reinterpret_cast<float2*>(&y[(size_t)node * HD + 2 * l]) = make_float2(y0, y1);
            s0 += y0; s1 += y1; q0 += y0 * y0; q1 += y1 * y1;
        }
    }
    __shared__ float ls[4][32], lq[4][32];
    if (grp == 0) {
        ls[wave][2 * l] = s0; ls[wave][2 * l + 1] = s1;
        lq[wave][2 * l] = q0; lq[wave][2 * l + 1] = q1;
    }
    __syncthreads();
    if (threadIdx.x < 32) {
        float a = ls[0][threadIdx.x] + ls[1][threadIdx.x] + ls[2][threadIdx.x] + ls[3][threadIdx.x];
        float b = lq[0][threadIdx.x] + lq[1][threadIdx.x] + lq[2][threadIdx.x] + lq[3][threadIdx.x];
        atomicAdd(&stats[threadIdx.x], a);
        atomicAdd(&stats[32 + threadIdx.x], b);
    }
}

// ========= agg variant V2: 8-lane uint2 bf16 gather, 8 grps, 2-deep (16 in flight) =========
__global__ void aggV2_kernel(const uint2* __restrict__ hb2, const int* __restrict__ offs,
                             const int2* __restrict__ centry, const float* __restrict__ dis,
                             const float* __restrict__ bias, float* __restrict__ y,
                             float* __restrict__ stats, int n) {
    int wave = threadIdx.x >> 6, lane = threadIdx.x & 63;
    int grp = lane >> 3, l = lane & 7;                 // lane l holds features 4l..4l+3
    float4 bv = *reinterpret_cast<const float4*>(bias + 4 * l);
    float s0 = 0.f, s1 = 0.f, s2 = 0.f, s3 = 0.f;
    float q0 = 0.f, q1 = 0.f, q2 = 0.f, q3 = 0.f;
    int base = (blockIdx.x * 4 + wave) * NPW;
    for (int t = 0; t < NPW; t++) {
        int node = base + t;
        if (node >= n) break;
        int s = offs[node], e2 = offs[node + 1];
        float a0 = 0.f, a1 = 0.f, a2 = 0.f, a3 = 0.f;
        float c0 = 0.f, c1 = 0.f, c2 = 0.f, c3 = 0.f;
        if (grp == 0) {
            float d = dis[node];
            float dd = d * d;
            uint2 hv = hb2[(size_t)node * 8 + l];
            a0 = bf_lo(hv.x) * dd; a1 = bf_hi(hv.x) * dd;
            a2 = bf_lo(hv.y) * dd; a3 = bf_hi(hv.y) * dd;
        }
        int j = s + grp;
        for (; j + 8 < e2; j += 16) {
            ull pa = nt_ld64(centry + j);
            ull pb = nt_ld64(centry + j + 8);
            uint2 ha = hb2[(size_t)(uint)pa * 8 + l];
            uint2 hc = hb2[(size_t)(uint)pb * 8 + l];
            float wa = __uint_as_float((uint)(pa >> 32));
            float wb = __uint_as_float((uint)(pb >> 32));
            a0 += bf_lo(ha.x) * wa; a1 += bf_hi(ha.x) * wa;
            a2 += bf_lo(ha.y) * wa; a3 += bf_hi(ha.y) * wa;
            c0 += bf_lo(hc.x) * wb; c1 += bf_hi(hc.x) * wb;
            c2 += bf_lo(hc.y) * wb; c3 += bf_hi(hc.y) * wb;
        }
        if (j < e2) {
            ull pa = nt_ld64(centry + j);
            uint2 ha = hb2[(size_t)(uint)pa * 8 + l];
            float wa = __uint_as_float((uint)(pa >> 32));
            a0 += bf_lo(ha.x) * wa; a1 += bf_hi(ha.x) * wa;
            a2 += bf_lo(ha.y) * wa; a3 += bf_hi(ha.y) * wa;
        }
        a0 += c0; a1 += c1; a2 += c2; a3 += c3;
#pragma unroll
        for (int d = 8; d <= 32; d <<= 1) {
            a0 += __shfl_xor(a0, d, 64); a1 += __shfl_xor(a1, d, 64);
            a2 += __shfl_xor(a2, d, 64); a3 += __shfl_xor(a3, d, 64);
        }
        float y0 = fmaxf(a0 + bv.x, 0.f), y1 = fmaxf(a1 + bv.y, 0.f);
        float y2 = fmaxf(a2 + bv.z, 0.f), y3 = fmaxf(a3 + bv.w, 0.f);
        if (grp == 0) {
            *reinterpret_cast<float4*>(&y[(size_t)node * HD + 4 * l]) = make_float4(y0, y1, y2, y3);
            s0 += y0; s1 += y1; s2 += y2; s3 += y3;
            q0 += y0 * y0; q1 += y1 * y1; q2 += y2 * y2; q3 += y3 * y3;
        }
    }
    __shared__ float ls[4][32], lq[4][32];
    if (grp == 0) {
        ls[wave][4 * l] = s0; ls[wave][4 * l + 1] = s1;
        ls[wave][4 * l + 2] = s2; ls[wave][4 * l + 3] = s3;
        lq[wave][4 * l] = q0; lq[wave][4 * l + 1] = q1;
        lq[wave][4 * l + 2] = q2; lq[wave][4 * l + 3] = q3;
    }
    __syncthreads();
    if (threadIdx.x < 32) {
        float a = ls[0][threadIdx.x] + ls[1][threadIdx.x] + ls[2][threadIdx.x] + ls[3][threadIdx.x];
        float b = lq[0][threadIdx.x] + lq[1][threadIdx.x] + lq[2][threadIdx.x] + lq[3][threadIdx.x];
        atomicAdd(&stats[threadIdx.x], a);
        atomicAdd(&stats[32 + threadIdx.x], b);
    }
}

// ---------- final linear: bn(y1..3) concat [N,96] @ [96,2] + bl; BN inline ----------
__global__ void final_kernel(const float* __restrict__ y1, const float* __restrict__ y2,
                             const float* __restrict__ y3,
                             const float* __restrict__ s1, const float* __restrict__ s2,
                             const float* __restrict__ s3,
                             const float* __restrict__ g1, const float* __restrict__ be1,
                             const float* __restrict__ g2, const float* __restrict__ be2,
                             const float* __restrict__ g3, const float* __restrict__ be3,
                             const float* __restrict__ Wl, const float* __restrict__ bl,
                             float* __restrict__ out, int n) {
    __shared__ float Ws[96 * NCLS];
    __shared__ float scs[3][64];
    __shared__ float bs[NCLS];
    for (int i = threadIdx.x; i < 96 * NCLS; i += blockDim.x) Ws[i] = Wl[i];
    if (threadIdx.x < 96) {
        int L = threadIdx.x >> 5, h = threadIdx.x & 31;
        const float* st = (L == 0) ? s1 : (L == 1) ? s2 : s3;
        const float* gg = (L == 0) ? g1 : (L == 1) ? g2 : g3;
        const float* bb = (L == 0) ? be1 : (L == 1) ? be2 : be3;
        float invn = 1.0f / (float)n;
        float mean = st[h] * invn;
        float var = st[32 + h] * invn - mean * mean;
        float sca = rsqrtf(var + BN_EPS) * gg[h];
        scs[L][h] = sca;
        scs[L][32 + h] = bb[h] - mean * sca;
    }
    if (threadIdx.x < NCLS) bs[threadIdx.x] = bl[threadIdx.x];
    __syncthreads();
    int i = blockIdx.x * blockDim.x + threadIdx.x;
    if (i >= n) return;
    float a0 = bs[0], a1 = bs[1];
    const float* ys[3] = {y1 + (size_t)i * HD, y2 + (size_t)i * HD, y3 + (size_t)i * HD};
#pragma unroll
    for (int L = 0; L < 3; L++) {
        const float4* r4 = reinterpret_cast<const float4*>(ys[L]);
#pragma unroll
        for (int q = 0; q < HD / 4; q++) {
            float4 v4 = r4[q];
            float vs[4] = {v4.x, v4.y, v4.z, v4.w};
#pragma unroll
            for (int j = 0; j < 4; j++) {
                int h = q * 4 + j;
                float v = vs[j] * scs[L][h] + scs[L][32 + h];
                a0 += v * Ws[(L * 32 + h) * 2];
                a1 += v * Ws[(L * 32 + h) * 2 + 1];
            }
        }
    }
    out[(size_t)i * 2] = a0;
    out[(size_t)i * 2 + 1] = a1;
}

extern "C" void kernel_launch(void* const* d_in, const int* in_sizes, int n_in,
                              void* d_out, int out_size, void* d_ws, size_t ws_size,
                              hipStream_t stream) {
    const float* x  = (const float*)d_in[0];
    const int*   ei = (const int*)d_in[1];
    const float* ew = (const float*)d_in[2];
    const float* W1 = (const float*)d_in[3];  const float* b1  = (const float*)d_in[4];
    const float* g1 = (const float*)d_in[5];  const float* be1 = (const float*)d_in[6];
    const float* W2 = (const float*)d_in[7];  const float* b2  = (const float*)d_in[8];
    const float* g2 = (const float*)d_in[9];  const float* be2 = (const float*)d_in[10];
    const float* W3 = (const float*)d_in[11]; const float* b3  = (const float*)d_in[12];
    const float* g3 = (const float*)d_in[13]; const float* be3 = (const float*)d_in[14];
    const float* Wl = (const float*)d_in[15]; const float* bl  = (const float*)d_in[16];

    int n = in_sizes[0] / F_IN;
    int E = in_sizes[1] / 2;

    char* ws = (char*)d_ws;
    auto alloc = [&](size_t bytes) -> char* {
        char* p = ws;
        ws += (bytes + 255) / 256 * 256;
        return p;
    };
    ull*    packed = (ull*)alloc((size_t)n * 8);
    float*  dis    = (float*)alloc((size_t)n * 4);
    int*    offs   = (int*)alloc((size_t)(n + 1) * 4);
    int*    partial= (int*)alloc(256 * 4);
    ushort* epos   = (ushort*)alloc((size_t)E * 2);
    int2*   centry = (int2*)alloc((size_t)E * 8);
    float*  hf     = (float*)alloc((size_t)n * HD * 4);
    ushort* hb     = (ushort*)alloc((size_t)n * HD * 2);
    float*  y1     = (float*)alloc((size_t)n * HD * 4);
    float*  y2     = (float*)alloc((size_t)n * HD * 4);
    float*  y3     = (float*)alloc((size_t)n * HD * 4);
    float*  stats1 = (float*)alloc(64 * 4);
    float*  stats2 = (float*)alloc(64 * 4);
    float*  stats3 = (float*)alloc(64 * 4);

    hipMemsetAsync(packed, 0, (size_t)n * 8, stream);

    int eb  = (E + 255) / 256;
    int nb  = (n + 255) / 256;
    int nhb = (n * HD + 255) / 256;
    int scb = (n + SCHUNK - 1) / SCHUNK;            // 98 for n=100000 (<=256 required)
    int aggb = (n + 4 * NPW - 1) / (4 * NPW);

    hist64_kernel<<<eb, 256, 0, stream>>>(ei, ew, packed, epos, E);
    scanA_kernel<<<scb, 256, 0, stream>>>(packed, partial, dis, n);
    scanB_kernel<<<1, 256, 0, stream>>>(partial, scb, offs + n);
    scanC_kernel<<<scb, 256, 0, stream>>>(packed, partial, offs, n);
    fill_kernel<<<eb, 256, 0, stream>>>(ei, ew, dis, offs, epos, centry, E);

    // layer 1 — V0 (32-lane fp32 gather)
    gemm_kernel<F_IN, false><<<nhb, 256, 0, stream>>>(x, W1, nullptr, nullptr, nullptr, hf, hb, stats1, n);
    aggV0_kernel<<<aggb, 256, 0, stream>>>(hf, offs, centry, dis, b1, y1, stats1, n);
    // layer 2 — V1 (16-lane bf16 gather)
    gemm_kernel<HD, true><<<nhb, 256, 0, stream>>>(y1, W2, stats1, g1, be1, hf, hb, stats2, n);
    aggV1_kernel<<<aggb, 256, 0, stream>>>((const uint*)hb, offs, centry, dis, b2, y2, stats2, n);
    // layer 3 — V2 (8-lane uint2 bf16 gather, 16 in flight)
    gemm_kernel<HD, true><<<nhb, 256, 0, stream>>>(y2, W3, stats2, g2, be2, hf, hb, stats3, n);
    aggV2_kernel<<<aggb, 256, 0, stream>>>((const uint2*)hb, offs, centry, dis, b3, y3, stats3, n);

    final_kernel<<<nb, 256, 0, stream>>>(y1, y2, y3, stats1, stats2, stats3,
                                         g1, be1, g2, be2, g3, be3, Wl, bl, (float*)d_out, n);
}

// Round 6
// 552.690 us; speedup vs baseline: 1.0452x; 1.0452x over previous
//
#include <hip/hip_runtime.h>

typedef unsigned int uint;
typedef unsigned short ushort;
typedef unsigned long long ull;

#define F_IN 64
#define HD 32
#define NCLS 2
#define BN_EPS 1e-5f
#define SCHUNK 1024
#define NPW 8
#define FIX_SCALE 1073741824.0f            // 2^30
#define FIX_INV   9.313225746154785e-10f   // 2^-30
#define MASK40 ((1ULL << 40) - 1)

__device__ __forceinline__ ull ld64(const int2* p) {
    return *reinterpret_cast<const ull*>(p);
}

// ---------- fused histogram: u64 atomic = count(hi24)+fixedpoint deg(lo40); epos = rank ----------
__global__ void hist64_kernel(const int* __restrict__ ei, const float* __restrict__ w,
                              ull* __restrict__ packed, ushort* __restrict__ epos, int E) {
    int e = blockIdx.x * blockDim.x + threadIdx.x;
    if (e >= E) return;
    int c = ei[E + e];
    ull fx = (ull)(w[e] * FIX_SCALE + 0.5f);
    ull old = atomicAdd(&packed[c], (1ULL << 40) | fx);
    epos[e] = (ushort)(old >> 40);
}

// ---------- scan phase A: per-chunk counts-sums; fused dis = rsqrt(deg+1) ----------
__global__ void scanA_kernel(const ull* __restrict__ packed,
                             int* __restrict__ partial, float* __restrict__ dis, int n) {
    __shared__ int red[256];
    int base = blockIdx.x * SCHUNK;
    int tid = threadIdx.x;
    int s = 0;
    for (int i = tid; i < SCHUNK; i += 256) {
        int idx = base + i;
        if (idx < n) {
            ull p = packed[idx];
            s += (int)(p >> 40);
            float deg = (float)(p & MASK40) * FIX_INV;
            dis[idx] = rsqrtf(deg + 1.0f);   // self-loop weight 1; arg >= 1
        }
    }
    red[tid] = s;
    __syncthreads();
    for (int off = 128; off > 0; off >>= 1) {
        if (tid < off) red[tid] += red[tid + off];
        __syncthreads();
    }
    if (tid == 0) partial[blockIdx.x] = red[0];
}

// ---------- scan phase B ----------
__global__ void scanB_kernel(int* __restrict__ partial, int nb, int* __restrict__ offs_n) {
    __shared__ int lds[256];
    int tid = threadIdx.x;
    int v = (tid < nb) ? partial[tid] : 0;
    lds[tid] = v;
    __syncthreads();
    for (int off = 1; off < 256; off <<= 1) {
        int t = (tid >= off) ? lds[tid - off] : 0;
        __syncthreads();
        lds[tid] += t;
        __syncthreads();
    }
    if (tid < nb) partial[tid] = lds[tid] - v;
    if (tid == nb - 1) *offs_n = lds[tid];
}

// ---------- scan phase C ----------
__global__ void scanC_kernel(const ull* __restrict__ packed, const int* __restrict__ partial,
                             int* __restrict__ offs, int n) {
    __shared__ int lds[256];
    int tid = threadIdx.x;
    int i0 = blockIdx.x * SCHUNK + tid * 4;
    int c0 = 0, c1 = 0, c2 = 0, c3 = 0;
    if (i0 + 0 < n) c0 = (int)(packed[i0 + 0] >> 40);
    if (i0 + 1 < n) c1 = (int)(packed[i0 + 1] >> 40);
    if (i0 + 2 < n) c2 = (int)(packed[i0 + 2] >> 40);
    if (i0 + 3 < n) c3 = (int)(packed[i0 + 3] >> 40);
    int tsum = c0 + c1 + c2 + c3;
    lds[tid] = tsum;
    __syncthreads();
    for (int off = 1; off < 256; off <<= 1) {
        int t = (tid >= off) ? lds[tid - off] : 0;
        __syncthreads();
        lds[tid] += t;
        __syncthreads();
    }
    int run = partial[blockIdx.x] + lds[tid] - tsum;
    int o0 = run, o1 = o0 + c0, o2 = o1 + c1, o3 = o2 + c2;
    if (i0 + 0 < n) offs[i0 + 0] = o0;
    if (i0 + 1 < n) offs[i0 + 1] = o1;
    if (i0 + 2 < n) offs[i0 + 2] = o2;
    if (i0 + 3 < n) offs[i0 + 3] = o3;
}

// ---------- fill CSR (atomic-free): pos = offs[col] + epos[e] ----------
__global__ void fill_kernel(const int* __restrict__ ei, const float* __restrict__ w,
                            const float* __restrict__ dis, const int* __restrict__ offs,
                            const ushort* __restrict__ epos, int2* __restrict__ centry, int E) {
    int e = blockIdx.x * blockDim.x + threadIdx.x;
    if (e >= E) return;
    int r = ei[e], c = ei[E + e];
    float nw = dis[r] * w[e] * dis[c];
    int pos = offs[c] + (int)epos[e];
    centry[pos] = make_int2(r, __float_as_int(nw));
}

// ---------- small GEMM: Hf[N,32] = bn?(X)[N,FIN] @ W[FIN,32]; BN inline; zeroes statsCur ----------
template <int FIN, bool BN>
__global__ void gemm_kernel(const float* __restrict__ X, const float* __restrict__ W,
                            const float* __restrict__ statsPrev, const float* __restrict__ g,
                            const float* __restrict__ be, float* __restrict__ Hf,
                            float* __restrict__ statsCur, int n) {
    __shared__ float Wl[FIN * HD];
    __shared__ float scl[64];
    for (int i = threadIdx.x; i < FIN * HD; i += blockDim.x) Wl[i] = W[i];
    if (BN && threadIdx.x < 32) {
        int h = threadIdx.x;
        float invn = 1.0f / (float)n;
        float mean = statsPrev[h] * invn;
        float var = statsPrev[32 + h] * invn - mean * mean;   // biased
        float sca = rsqrtf(var + BN_EPS) * g[h];
        scl[h] = sca;
        scl[32 + h] = be[h] - mean * sca;
    }
    if (blockIdx.x == 0 && threadIdx.x < 64) statsCur[threadIdx.x] = 0.0f;
    __syncthreads();
    int idx = blockIdx.x * blockDim.x + threadIdx.x;
    if (idx >= n * HD) return;
    int node = idx >> 5, h = idx & 31;
    const float4* xr4 = reinterpret_cast<const float4*>(X + (size_t)node * FIN);
    float acc = 0.0f;
#pragma unroll
    for (int q = 0; q < FIN / 4; q++) {
        float4 v4 = xr4[q];
        float vs[4] = {v4.x, v4.y, v4.z, v4.w};
#pragma unroll
        for (int j = 0; j < 4; j++) {
            int k = q * 4 + j;
            float v = vs[j];
            if (BN) v = v * scl[k] + scl[32 + k];
            acc += v * Wl[k * HD + h];
        }
    }
    Hf[idx] = acc;
}

// ================= V0: 32-lane fp32 gather, 2 subs, 2-deep (4 in flight) =================
__global__ void aggV0_kernel(const float* __restrict__ hf, const int* __restrict__ offs,
                             const int2* __restrict__ centry, const float* __restrict__ dis,
                             const float* __restrict__ bias, float* __restrict__ y,
                             float* __restrict__ stats, int n) {
    int wave = threadIdx.x >> 6, lane = threadIdx.x & 63, sub = lane >> 5, h = lane & 31;
    float bv = bias[h];
    float lsum = 0.f, lsq = 0.f;
    int base = (blockIdx.x * 4 + wave) * NPW;
    for (int t = 0; t < NPW; t++) {
        int node = base + t;
        if (node >= n) break;
        int s = offs[node], e2 = offs[node + 1];
        float acc = 0.f, acc2 = 0.f;
        if (sub == 0) {
            float d = dis[node];
            acc = hf[(size_t)node * HD + h] * d * d;
        }
        int j = s + sub;
        for (; j + 2 < e2; j += 4) {
            ull pa = ld64(centry + j);
            ull pb = ld64(centry + j + 2);
            float wa = __uint_as_float((uint)(pa >> 32));
            float wb = __uint_as_float((uint)(pb >> 32));
            acc  += hf[(size_t)(uint)pa * HD + h] * wa;
            acc2 += hf[(size_t)(uint)pb * HD + h] * wb;
        }
        if (j < e2) {
            ull pa = ld64(centry + j);
            float wa = __uint_as_float((uint)(pa >> 32));
            acc += hf[(size_t)(uint)pa * HD + h] * wa;
        }
        acc += acc2;
        acc += __shfl_xor(acc, 32, 64);
        float yv = fmaxf(acc + bv, 0.f);
        if (sub == 0) {
            y[(size_t)node * HD + h] = yv;
            lsum += yv; lsq += yv * yv;
        }
    }
    __shared__ float ls[4][32], lq[4][32];
    if (sub == 0) { ls[wave][h] = lsum; lq[wave][h] = lsq; }
    __syncthreads();
    if (threadIdx.x < 32) {
        float a = ls[0][threadIdx.x] + ls[1][threadIdx.x] + ls[2][threadIdx.x] + ls[3][threadIdx.x];
        float b = lq[0][threadIdx.x] + lq[1][threadIdx.x] + lq[2][threadIdx.x] + lq[3][threadIdx.x];
        atomicAdd(&stats[threadIdx.x], a);
        atomicAdd(&stats[32 + threadIdx.x], b);
    }
}

// ================= V0deep: 32-lane fp32 gather, 2 subs, 4-deep (8 in flight) =================
__global__ void aggV0d_kernel(const float* __restrict__ hf, const int* __restrict__ offs,
                              const int2* __restrict__ centry, const float* __restrict__ dis,
                              const float* __restrict__ bias, float* __restrict__ y,
                              float* __restrict__ stats, int n) {
    int wave = threadIdx.x >> 6, lane = threadIdx.x & 63, sub = lane >> 5, h = lane & 31;
    float bv = bias[h];
    float lsum = 0.f, lsq = 0.f;
    int base = (blockIdx.x * 4 + wave) * NPW;
    for (int t = 0; t < NPW; t++) {
        int node = base + t;
        if (node >= n) break;
        int s = offs[node], e2 = offs[node + 1];
        float a0 = 0.f, a1 = 0.f, a2 = 0.f, a3 = 0.f;
        if (sub == 0) {
            float d = dis[node];
            a0 = hf[(size_t)node * HD + h] * d * d;
        }
        int j = s + sub;
        for (; j + 6 < e2; j += 8) {
            ull p0 = ld64(centry + j);
            ull p1 = ld64(centry + j + 2);
            ull p2 = ld64(centry + j + 4);
            ull p3 = ld64(centry + j + 6);
            a0 += hf[(size_t)(uint)p0 * HD + h] * __uint_as_float((uint)(p0 >> 32));
            a1 += hf[(size_t)(uint)p1 * HD + h] * __uint_as_float((uint)(p1 >> 32));
            a2 += hf[(size_t)(uint)p2 * HD + h] * __uint_as_float((uint)(p2 >> 32));
            a3 += hf[(size_t)(uint)p3 * HD + h] * __uint_as_float((uint)(p3 >> 32));
        }
        for (; j < e2; j += 2) {
            ull p0 = ld64(centry + j);
            a0 += hf[(size_t)(uint)p0 * HD + h] * __uint_as_float((uint)(p0 >> 32));
        }
        a0 += a1 + a2 + a3;
        a0 += __shfl_xor(a0, 32, 64);
        float yv = fmaxf(a0 + bv, 0.f);
        if (sub == 0) {
            y[(size_t)node * HD + h] = yv;
            lsum += yv; lsq += yv * yv;
        }
    }
    __shared__ float ls[4][32], lq[4][32];
    if (sub == 0) { ls[wave][h] = lsum; lq[wave][h] = lsq; }
    __syncthreads();
    if (threadIdx.x < 32) {
        float a = ls[0][threadIdx.x] + ls[1][threadIdx.x] + ls[2][threadIdx.x] + ls[3][threadIdx.x];
        float b = lq[0][threadIdx.x] + lq[1][threadIdx.x] + lq[2][threadIdx.x] + lq[3][threadIdx.x];
        atomicAdd(&stats[threadIdx.x], a);
        atomicAdd(&stats[32 + threadIdx.x], b);
    }
}

// ========= V3: 16-lane float2 fp32 gather, 4 grps, 2-deep (8 in flight) =========
__global__ void aggV3_kernel(const float2* __restrict__ hf2, const int* __restrict__ offs,
                             const int2* __restrict__ centry, const float* __restrict__ dis,
                             const float* __restrict__ bias, float* __restrict__ y,
                             float* __restrict__ stats, int n) {
    int wave = threadIdx.x >> 6, lane = threadIdx.x & 63;
    int grp = lane >> 4, l = lane & 15;                // lane holds features {2l, 2l+1}
    float b0 = bias[2 * l], b1 = bias[2 * l + 1];
    float s0 = 0.f, s1 = 0.f, q0 = 0.f, q1 = 0.f;
    int base = (blockIdx.x * 4 + wave) * NPW;
    for (int t = 0; t < NPW; t++) {
        int node = base + t;
        if (node >= n) break;
        int s = offs[node], e2 = offs[node + 1];
        float a0 = 0.f, a1 = 0.f, c0 = 0.f, c1 = 0.f;
        if (grp == 0) {
            float d = dis[node];
            float dd = d * d;
            float2 hv = hf2[(size_t)node * 16 + l];
            a0 = hv.x * dd; a1 = hv.y * dd;
        }
        int j = s + grp;
        for (; j + 4 < e2; j += 8) {
            ull pa = ld64(centry + j);
            ull pb = ld64(centry + j + 4);
            float2 ha = hf2[(size_t)(uint)pa * 16 + l];
            float2 hc = hf2[(size_t)(uint)pb * 16 + l];
            float wa = __uint_as_float((uint)(pa >> 32));
            float wb = __uint_as_float((uint)(pb >> 32));
            a0 += ha.x * wa; a1 += ha.y * wa;
            c0 += hc.x * wb; c1 += hc.y * wb;
        }
        if (j < e2) {
            ull pa = ld64(centry + j);
            float2 ha = hf2[(size_t)(uint)pa * 16 + l];
            float wa = __uint_as_float((uint)(pa >> 32));
            a0 += ha.x * wa; a1 += ha.y * wa;
        }
        a0 += c0; a1 += c1;
        a0 += __shfl_xor(a0, 16, 64); a1 += __shfl_xor(a1, 16, 64);
        a0 += __shfl_xor(a0, 32, 64); a1 += __shfl_xor(a1, 32, 64);
        float y0 = fmaxf(a0 + b0, 0.f), y1 = fmaxf(a1 + b1, 0.f);
        if (grp == 0) {
            *reinterpret_cast<float2*>(&y[(size_t)node * HD + 2 * l]) = make_float2(y0, y1);
            s0 += y0; s1 += y1; q0 += y0 * y0; q1 += y1 * y1;
        }
    }
    __shared__ float ls[4][32], lq[4][32];
    if (grp == 0) {
        ls[wave][2 * l] = s0; ls[wave][2 * l + 1] = s1;
        lq[wave][2 * l] = q0; lq[wave][2 * l + 1] = q1;
    }
    __syncthreads();
    if (threadIdx.x < 32) {
        float a = ls[0][threadIdx.x] + ls[1][threadIdx.x] + ls[2][threadIdx.x] + ls[3][threadIdx.x];
        float b = lq[0][threadIdx.x] + lq[1][threadIdx.x] + lq[2][threadIdx.x] + lq[3][threadIdx.x];
        atomicAdd(&stats[threadIdx.x], a);
        atomicAdd(&stats[32 + threadIdx.x], b);
    }
}

// ---------- final linear: bn(y1..3) concat [N,96] @ [96,2] + bl; BN inline ----------
__global__ void final_kernel(const float* __restrict__ y1, const float* __restrict__ y2,
                             const float* __restrict__ y3,
                             const float* __restrict__ s1, const float* __restrict__ s2,
                             const float* __restrict__ s3,
                             const float* __restrict__ g1, const float* __restrict__ be1,
                             const float* __restrict__ g2, const float* __restrict__ be2,
                             const float* __restrict__ g3, const float* __restrict__ be3,
                             const float* __restrict__ Wl, const float* __restrict__ bl,
                             float* __restrict__ out, int n) {
    __shared__ float Ws[96 * NCLS];
    __shared__ float scs[3][64];
    __shared__ float bs[NCLS];
    for (int i = threadIdx.x; i < 96 * NCLS; i += blockDim.x) Ws[i] = Wl[i];
    if (threadIdx.x < 96) {
        int L = threadIdx.x >> 5, h = threadIdx.x & 31;
        const float* st = (L == 0) ? s1 : (L == 1) ? s2 : s3;
        const float* gg = (L == 0) ? g1 : (L == 1) ? g2 : g3;
        const float* bb = (L == 0) ? be1 : (L == 1) ? be2 : be3;
        float invn = 1.0f / (float)n;
        float mean = st[h] * invn;
        float var = st[32 + h] * invn - mean * mean;
        float sca = rsqrtf(var + BN_EPS) * gg[h];
        scs[L][h] = sca;
        scs[L][32 + h] = bb[h] - mean * sca;
    }
    if (threadIdx.x < NCLS) bs[threadIdx.x] = bl[threadIdx.x];
    __syncthreads();
    int i = blockIdx.x * blockDim.x + threadIdx.x;
    if (i >= n) return;
    float a0 = bs[0], a1 = bs[1];
    const float* ys[3] = {y1 + (size_t)i * HD, y2 + (size_t)i * HD, y3 + (size_t)i * HD};
#pragma unroll
    for (int L = 0; L < 3; L++) {
        const float4* r4 = reinterpret_cast<const float4*>(ys[L]);
#pragma unroll
        for (int q = 0; q < HD / 4; q++) {
            float4 v4 = r4[q];
            float vs[4] = {v4.x, v4.y, v4.z, v4.w};
#pragma unroll
            for (int j = 0; j < 4; j++) {
                int h = q * 4 + j;
                float v = vs[j] * scs[L][h] + scs[L][32 + h];
                a0 += v * Ws[(L * 32 + h) * 2];
                a1 += v * Ws[(L * 32 + h) * 2 + 1];
            }
        }
    }
    out[(size_t)i * 2] = a0;
    out[(size_t)i * 2 + 1] = a1;
}

extern "C" void kernel_launch(void* const* d_in, const int* in_sizes, int n_in,
                              void* d_out, int out_size, void* d_ws, size_t ws_size,
                              hipStream_t stream) {
    const float* x  = (const float*)d_in[0];
    const int*   ei = (const int*)d_in[1];
    const float* ew = (const float*)d_in[2];
    const float* W1 = (const float*)d_in[3];  const float* b1  = (const float*)d_in[4];
    const float* g1 = (const float*)d_in[5];  const float* be1 = (const float*)d_in[6];
    const float* W2 = (const float*)d_in[7];  const float* b2  = (const float*)d_in[8];
    const float* g2 = (const float*)d_in[9];  const float* be2 = (const float*)d_in[10];
    const float* W3 = (const float*)d_in[11]; const float* b3  = (const float*)d_in[12];
    const float* g3 = (const float*)d_in[13]; const float* be3 = (const float*)d_in[14];
    const float* Wl = (const float*)d_in[15]; const float* bl  = (const float*)d_in[16];

    int n = in_sizes[0] / F_IN;
    int E = in_sizes[1] / 2;

    char* ws = (char*)d_ws;
    auto alloc = [&](size_t bytes) -> char* {
        char* p = ws;
        ws += (bytes + 255) / 256 * 256;
        return p;
    };
    ull*    packed = (ull*)alloc((size_t)n * 8);
    float*  dis    = (float*)alloc((size_t)n * 4);
    int*    offs   = (int*)alloc((size_t)(n + 1) * 4);
    int*    partial= (int*)alloc(256 * 4);
    ushort* epos   = (ushort*)alloc((size_t)E * 2);
    int2*   centry = (int2*)alloc((size_t)E * 8);
    float*  hf     = (float*)alloc((size_t)n * HD * 4);
    float*  y1     = (float*)alloc((size_t)n * HD * 4);
    float*  y2     = (float*)alloc((size_t)n * HD * 4);
    float*  y3     = (float*)alloc((size_t)n * HD * 4);
    float*  stats1 = (float*)alloc(64 * 4);
    float*  stats2 = (float*)alloc(64 * 4);
    float*  stats3 = (float*)alloc(64 * 4);

    hipMemsetAsync(packed, 0, (size_t)n * 8, stream);

    int eb  = (E + 255) / 256;
    int nb  = (n + 255) / 256;
    int nhb = (n * HD + 255) / 256;
    int scb = (n + SCHUNK - 1) / SCHUNK;            // 98 for n=100000 (<=256 required)
    int aggb = (n + 4 * NPW - 1) / (4 * NPW);

    hist64_kernel<<<eb, 256, 0, stream>>>(ei, ew, packed, epos, E);
    scanA_kernel<<<scb, 256, 0, stream>>>(packed, partial, dis, n);
    scanB_kernel<<<1, 256, 0, stream>>>(partial, scb, offs + n);
    scanC_kernel<<<scb, 256, 0, stream>>>(packed, partial, offs, n);
    fill_kernel<<<eb, 256, 0, stream>>>(ei, ew, dis, offs, epos, centry, E);

    // layer 1 — V0 control (4 gathers in flight)
    gemm_kernel<F_IN, false><<<nhb, 256, 0, stream>>>(x, W1, nullptr, nullptr, nullptr, hf, stats1, n);
    aggV0_kernel<<<aggb, 256, 0, stream>>>(hf, offs, centry, dis, b1, y1, stats1, n);
    // layer 2 — V0deep (8 in flight, same shape)
    gemm_kernel<HD, true><<<nhb, 256, 0, stream>>>(y1, W2, stats1, g1, be1, hf, stats2, n);
    aggV0d_kernel<<<aggb, 256, 0, stream>>>(hf, offs, centry, dis, b2, y2, stats2, n);
    // layer 3 — V3 (16-lane float2, 8 in flight)
    gemm_kernel<HD, true><<<nhb, 256, 0, stream>>>(y2, W3, stats2, g2, be2, hf, stats3, n);
    aggV3_kernel<<<aggb, 256, 0, stream>>>((const float2*)hf, offs, centry, dis, b3, y3, stats3, n);

    final_kernel<<<nb, 256, 0, stream>>>(y1, y2, y3, stats1, stats2, stats3,
                                         g1, be1, g2, be2, g3, be3, Wl, bl, (float*)d_out, n);
}

// Round 7
// 479.124 us; speedup vs baseline: 1.2057x; 1.1535x over previous
//
#include <hip/hip_runtime.h>

typedef unsigned int uint;
typedef unsigned short ushort;
typedef unsigned long long ull;

#define F_IN 64
#define HD 32
#define NCLS 2
#define BN_EPS 1e-5f
#define SCHUNK 1024
#define NPW 16
#define FIX_SCALE 1073741824.0f            // 2^30
#define FIX_INV   9.313225746154785e-10f   // 2^-30
#define MASK40 ((1ULL << 40) - 1)

__device__ __forceinline__ ull ld64(const int2* p) {
    return *reinterpret_cast<const ull*>(p);
}

// ---------- fused histogram: u64 atomic = count(hi24)+fixedpoint deg(lo40); epos = rank ----------
__global__ void hist64_kernel(const int* __restrict__ ei, const float* __restrict__ w,
                              ull* __restrict__ packed, ushort* __restrict__ epos, int E) {
    int e = blockIdx.x * blockDim.x + threadIdx.x;
    if (e >= E) return;
    int c = ei[E + e];
    ull fx = (ull)(w[e] * FIX_SCALE + 0.5f);
    ull old = atomicAdd(&packed[c], (1ULL << 40) | fx);
    epos[e] = (ushort)(old >> 40);
}

// ---------- scan phase A: per-chunk counts-sums; fused dis = rsqrt(deg+1) ----------
__global__ void scanA_kernel(const ull* __restrict__ packed,
                             int* __restrict__ partial, float* __restrict__ dis, int n) {
    __shared__ int red[256];
    int base = blockIdx.x * SCHUNK;
    int tid = threadIdx.x;
    int s = 0;
    for (int i = tid; i < SCHUNK; i += 256) {
        int idx = base + i;
        if (idx < n) {
            ull p = packed[idx];
            s += (int)(p >> 40);
            float deg = (float)(p & MASK40) * FIX_INV;
            dis[idx] = rsqrtf(deg + 1.0f);   // self-loop weight 1; arg >= 1
        }
    }
    red[tid] = s;
    __syncthreads();
    for (int off = 128; off > 0; off >>= 1) {
        if (tid < off) red[tid] += red[tid + off];
        __syncthreads();
    }
    if (tid == 0) partial[blockIdx.x] = red[0];
}

// ---------- scan phase B ----------
__global__ void scanB_kernel(int* __restrict__ partial, int nb, int* __restrict__ offs_n) {
    __shared__ int lds[256];
    int tid = threadIdx.x;
    int v = (tid < nb) ? partial[tid] : 0;
    lds[tid] = v;
    __syncthreads();
    for (int off = 1; off < 256; off <<= 1) {
        int t = (tid >= off) ? lds[tid - off] : 0;
        __syncthreads();
        lds[tid] += t;
        __syncthreads();
    }
    if (tid < nb) partial[tid] = lds[tid] - v;
    if (tid == nb - 1) *offs_n = lds[tid];
}

// ---------- scan phase C ----------
__global__ void scanC_kernel(const ull* __restrict__ packed, const int* __restrict__ partial,
                             int* __restrict__ offs, int n) {
    __shared__ int lds[256];
    int tid = threadIdx.x;
    int i0 = blockIdx.x * SCHUNK + tid * 4;
    int c0 = 0, c1 = 0, c2 = 0, c3 = 0;
    if (i0 + 0 < n) c0 = (int)(packed[i0 + 0] >> 40);
    if (i0 + 1 < n) c1 = (int)(packed[i0 + 1] >> 40);
    if (i0 + 2 < n) c2 = (int)(packed[i0 + 2] >> 40);
    if (i0 + 3 < n) c3 = (int)(packed[i0 + 3] >> 40);
    int tsum = c0 + c1 + c2 + c3;
    lds[tid] = tsum;
    __syncthreads();
    for (int off = 1; off < 256; off <<= 1) {
        int t = (tid >= off) ? lds[tid - off] : 0;
        __syncthreads();
        lds[tid] += t;
        __syncthreads();
    }
    int run = partial[blockIdx.x] + lds[tid] - tsum;
    int o0 = run, o1 = o0 + c0, o2 = o1 + c1, o3 = o2 + c2;
    if (i0 + 0 < n) offs[i0 + 0] = o0;
    if (i0 + 1 < n) offs[i0 + 1] = o1;
    if (i0 + 2 < n) offs[i0 + 2] = o2;
    if (i0 + 3 < n) offs[i0 + 3] = o3;
}

// ---------- fill CSR (atomic-free, no dis reads): centry[pos] = (row, raw_w) ----------
__global__ void fill_kernel(const int* __restrict__ ei, const float* __restrict__ w,
                            const int* __restrict__ offs, const ushort* __restrict__ epos,
                            int2* __restrict__ centry, int E) {
    int e = blockIdx.x * blockDim.x + threadIdx.x;
    if (e >= E) return;
    int r = ei[e], c = ei[E + e];
    int pos = offs[c] + (int)epos[e];
    centry[pos] = make_int2(r, __float_as_int(w[e]));
}

// ---------- small GEMM: Hf[N,32] = (bn?(X) @ W) * dis[node]  (dis folded in) ----------
template <int FIN, bool BN>
__global__ void gemm_kernel(const float* __restrict__ X, const float* __restrict__ W,
                            const float* __restrict__ statsPrev, const float* __restrict__ g,
                            const float* __restrict__ be, const float* __restrict__ dis,
                            float* __restrict__ Hf, float* __restrict__ statsCur, int n) {
    __shared__ float Wl[FIN * HD];
    __shared__ float scl[64];
    for (int i = threadIdx.x; i < FIN * HD; i += blockDim.x) Wl[i] = W[i];
    if (BN && threadIdx.x < 32) {
        int h = threadIdx.x;
        float invn = 1.0f / (float)n;
        float mean = statsPrev[h] * invn;
        float var = statsPrev[32 + h] * invn - mean * mean;   // biased
        float sca = rsqrtf(var + BN_EPS) * g[h];
        scl[h] = sca;
        scl[32 + h] = be[h] - mean * sca;
    }
    if (blockIdx.x == 0 && threadIdx.x < 64) statsCur[threadIdx.x] = 0.0f;
    __syncthreads();
    int idx = blockIdx.x * blockDim.x + threadIdx.x;
    if (idx >= n * HD) return;
    int node = idx >> 5, h = idx & 31;
    const float4* xr4 = reinterpret_cast<const float4*>(X + (size_t)node * FIN);
    float acc = 0.0f;
#pragma unroll
    for (int q = 0; q < FIN / 4; q++) {
        float4 v4 = xr4[q];
        float vs[4] = {v4.x, v4.y, v4.z, v4.w};
#pragma unroll
        for (int j = 0; j < 4; j++) {
            int k = q * 4 + j;
            float v = vs[j];
            if (BN) v = v * scl[k] + scl[32 + k];
            acc += v * Wl[k * HD + h];
        }
    }
    Hf[idx] = acc * dis[node];               // hlin' = h * dis
}

// y[c] = relu(bias + dis[c]*(hlin'[c] + sum_e w_e*hlin'[row_e]))   [dis factored out]
// ================= V0n: 32-lane gather, 2 interleaved subs, 2-deep (R3 shape) =================
__global__ void aggV0n_kernel(const float* __restrict__ hf, const int* __restrict__ offs,
                              const int2* __restrict__ centry, const float* __restrict__ dis,
                              const float* __restrict__ bias, float* __restrict__ y,
                              float* __restrict__ stats, int n) {
    int wave = threadIdx.x >> 6, lane = threadIdx.x & 63, sub = lane >> 5, h = lane & 31;
    float bv = bias[h];
    float lsum = 0.f, lsq = 0.f;
    int base = (blockIdx.x * 4 + wave) * NPW;
    for (int t = 0; t < NPW; t++) {
        int node = base + t;
        if (node >= n) break;
        int s = offs[node], e2 = offs[node + 1];
        float dd = dis[node];
        float acc = 0.f, acc2 = 0.f;
        if (sub == 0) acc = hf[(size_t)node * HD + h];      // self-loop (x dis later)
        int j = s + sub;
        for (; j + 2 < e2; j += 4) {
            ull pa = ld64(centry + j);
            ull pb = ld64(centry + j + 2);
            float wa = __uint_as_float((uint)(pa >> 32));
            float wb = __uint_as_float((uint)(pb >> 32));
            acc  += hf[(size_t)(uint)pa * HD + h] * wa;
            acc2 += hf[(size_t)(uint)pb * HD + h] * wb;
        }
        if (j < e2) {
            ull pa = ld64(centry + j);
            float wa = __uint_as_float((uint)(pa >> 32));
            acc += hf[(size_t)(uint)pa * HD + h] * wa;
        }
        acc += acc2;
        acc += __shfl_xor(acc, 32, 64);
        float yv = fmaxf(fmaf(acc, dd, bv), 0.f);
        if (sub == 0) {
            y[(size_t)node * HD + h] = yv;
            lsum += yv; lsq += yv * yv;
        }
    }
    __shared__ float ls[4][32], lq[4][32];
    if (sub == 0) { ls[wave][h] = lsum; lq[wave][h] = lsq; }
    __syncthreads();
    if (threadIdx.x < 32) {
        float a = ls[0][threadIdx.x] + ls[1][threadIdx.x] + ls[2][threadIdx.x] + ls[3][threadIdx.x];
        float b = lq[0][threadIdx.x] + lq[1][threadIdx.x] + lq[2][threadIdx.x] + lq[3][threadIdx.x];
        atomicAdd(&stats[threadIdx.x], a);
        atomicAdd(&stats[32 + threadIdx.x], b);
    }
}

// ====== V4n: contiguous-split subs, 4 consecutive ld64 preload -> 4 indep gathers ======
__global__ void aggV4n_kernel(const float* __restrict__ hf, const int* __restrict__ offs,
                              const int2* __restrict__ centry, const float* __restrict__ dis,
                              const float* __restrict__ bias, float* __restrict__ y,
                              float* __restrict__ stats, int n) {
    int wave = threadIdx.x >> 6, lane = threadIdx.x & 63, sub = lane >> 5, h = lane & 31;
    float bv = bias[h];
    float lsum = 0.f, lsq = 0.f;
    int base = (blockIdx.x * 4 + wave) * NPW;
    for (int t = 0; t < NPW; t++) {
        int node = base + t;
        if (node >= n) break;
        int s = offs[node], e2 = offs[node + 1];
        int len = e2 - s;
        int half = (len + 1) >> 1;
        int j    = sub ? (s + half) : s;          // contiguous halves
        int jend = sub ? e2 : (s + half);
        float dd = dis[node];
        float a0 = 0.f, a1 = 0.f, a2 = 0.f, a3 = 0.f;
        if (sub == 0) a0 = hf[(size_t)node * HD + h];       // self-loop
        for (; j + 3 < jend; j += 4) {
            ull p0 = ld64(centry + j);
            ull p1 = ld64(centry + j + 1);
            ull p2 = ld64(centry + j + 2);
            ull p3 = ld64(centry + j + 3);
            a0 += hf[(size_t)(uint)p0 * HD + h] * __uint_as_float((uint)(p0 >> 32));
            a1 += hf[(size_t)(uint)p1 * HD + h] * __uint_as_float((uint)(p1 >> 32));
            a2 += hf[(size_t)(uint)p2 * HD + h] * __uint_as_float((uint)(p2 >> 32));
            a3 += hf[(size_t)(uint)p3 * HD + h] * __uint_as_float((uint)(p3 >> 32));
        }
        for (; j < jend; j++) {
            ull p0 = ld64(centry + j);
            a0 += hf[(size_t)(uint)p0 * HD + h] * __uint_as_float((uint)(p0 >> 32));
        }
        a0 += a1 + a2 + a3;
        a0 += __shfl_xor(a0, 32, 64);
        float yv = fmaxf(fmaf(a0, dd, bv), 0.f);
        if (sub == 0) {
            y[(size_t)node * HD + h] = yv;
            lsum += yv; lsq += yv * yv;
        }
    }
    __shared__ float ls[4][32], lq[4][32];
    if (sub == 0) { ls[wave][h] = lsum; lq[wave][h] = lsq; }
    __syncthreads();
    if (threadIdx.x < 32) {
        float a = ls[0][threadIdx.x] + ls[1][threadIdx.x] + ls[2][threadIdx.x] + ls[3][threadIdx.x];
        float b = lq[0][threadIdx.x] + lq[1][threadIdx.x] + lq[2][threadIdx.x] + lq[3][threadIdx.x];
        atomicAdd(&stats[threadIdx.x], a);
        atomicAdd(&stats[32 + threadIdx.x], b);
    }
}

// ---------- final linear: bn(y1..3) concat [N,96] @ [96,2] + bl; BN inline ----------
__global__ void final_kernel(const float* __restrict__ y1, const float* __restrict__ y2,
                             const float* __restrict__ y3,
                             const float* __restrict__ s1, const float* __restrict__ s2,
                             const float* __restrict__ s3,
                             const float* __restrict__ g1, const float* __restrict__ be1,
                             const float* __restrict__ g2, const float* __restrict__ be2,
                             const float* __restrict__ g3, const float* __restrict__ be3,
                             const float* __restrict__ Wl, const float* __restrict__ bl,
                             float* __restrict__ out, int n) {
    __shared__ float Ws[96 * NCLS];
    __shared__ float scs[3][64];
    __shared__ float bs[NCLS];
    for (int i = threadIdx.x; i < 96 * NCLS; i += blockDim.x) Ws[i] = Wl[i];
    if (threadIdx.x < 96) {
        int L = threadIdx.x >> 5, h = threadIdx.x & 31;
        const float* st = (L == 0) ? s1 : (L == 1) ? s2 : s3;
        const float* gg = (L == 0) ? g1 : (L == 1) ? g2 : g3;
        const float* bb = (L == 0) ? be1 : (L == 1) ? be2 : be3;
        float invn = 1.0f / (float)n;
        float mean = st[h] * invn;
        float var = st[32 + h] * invn - mean * mean;
        float sca = rsqrtf(var + BN_EPS) * gg[h];
        scs[L][h] = sca;
        scs[L][32 + h] = bb[h] - mean * sca;
    }
    if (threadIdx.x < NCLS) bs[threadIdx.x] = bl[threadIdx.x];
    __syncthreads();
    int i = blockIdx.x * blockDim.x + threadIdx.x;
    if (i >= n) return;
    float a0 = bs[0], a1 = bs[1];
    const float* ys[3] = {y1 + (size_t)i * HD, y2 + (size_t)i * HD, y3 + (size_t)i * HD};
#pragma unroll
    for (int L = 0; L < 3; L++) {
        const float4* r4 = reinterpret_cast<const float4*>(ys[L]);
#pragma unroll
        for (int q = 0; q < HD / 4; q++) {
            float4 v4 = r4[q];
            float vs[4] = {v4.x, v4.y, v4.z, v4.w};
#pragma unroll
            for (int j = 0; j < 4; j++) {
                int h = q * 4 + j;
                float v = vs[j] * scs[L][h] + scs[L][32 + h];
                a0 += v * Ws[(L * 32 + h) * 2];
                a1 += v * Ws[(L * 32 + h) * 2 + 1];
            }
        }
    }
    out[(size_t)i * 2] = a0;
    out[(size_t)i * 2 + 1] = a1;
}

extern "C" void kernel_launch(void* const* d_in, const int* in_sizes, int n_in,
                              void* d_out, int out_size, void* d_ws, size_t ws_size,
                              hipStream_t stream) {
    const float* x  = (const float*)d_in[0];
    const int*   ei = (const int*)d_in[1];
    const float* ew = (const float*)d_in[2];
    const float* W1 = (const float*)d_in[3];  const float* b1  = (const float*)d_in[4];
    const float* g1 = (const float*)d_in[5];  const float* be1 = (const float*)d_in[6];
    const float* W2 = (const float*)d_in[7];  const float* b2  = (const float*)d_in[8];
    const float* g2 = (const float*)d_in[9];  const float* be2 = (const float*)d_in[10];
    const float* W3 = (const float*)d_in[11]; const float* b3  = (const float*)d_in[12];
    const float* g3 = (const float*)d_in[13]; const float* be3 = (const float*)d_in[14];
    const float* Wl = (const float*)d_in[15]; const float* bl  = (const float*)d_in[16];

    int n = in_sizes[0] / F_IN;
    int E = in_sizes[1] / 2;

    char* ws = (char*)d_ws;
    auto alloc = [&](size_t bytes) -> char* {
        char* p = ws;
        ws += (bytes + 255) / 256 * 256;
        return p;
    };
    ull*    packed = (ull*)alloc((size_t)n * 8);
    float*  dis    = (float*)alloc((size_t)n * 4);
    int*    offs   = (int*)alloc((size_t)(n + 1) * 4);
    int*    partial= (int*)alloc(256 * 4);
    ushort* epos   = (ushort*)alloc((size_t)E * 2);
    int2*   centry = (int2*)alloc((size_t)E * 8);
    float*  hf     = (float*)alloc((size_t)n * HD * 4);
    float*  y1     = (float*)alloc((size_t)n * HD * 4);
    float*  y2     = (float*)alloc((size_t)n * HD * 4);
    float*  y3     = (float*)alloc((size_t)n * HD * 4);
    float*  stats1 = (float*)alloc(64 * 4);
    float*  stats2 = (float*)alloc(64 * 4);
    float*  stats3 = (float*)alloc(64 * 4);

    hipMemsetAsync(packed, 0, (size_t)n * 8, stream);

    int eb  = (E + 255) / 256;
    int nb  = (n + 255) / 256;
    int nhb = (n * HD + 255) / 256;
    int scb = (n + SCHUNK - 1) / SCHUNK;            // 98 for n=100000 (<=256 required)
    int aggb = (n + 4 * NPW - 1) / (4 * NPW);

    hist64_kernel<<<eb, 256, 0, stream>>>(ei, ew, packed, epos, E);
    scanA_kernel<<<scb, 256, 0, stream>>>(packed, partial, dis, n);
    scanB_kernel<<<1, 256, 0, stream>>>(partial, scb, offs + n);
    scanC_kernel<<<scb, 256, 0, stream>>>(packed, partial, offs, n);
    fill_kernel<<<eb, 256, 0, stream>>>(ei, ew, offs, epos, centry, E);

    // layer 1 — V0n control (R3 shape, NPW=16)
    gemm_kernel<F_IN, false><<<nhb, 256, 0, stream>>>(x, W1, nullptr, nullptr, nullptr, dis, hf, stats1, n);
    aggV0n_kernel<<<aggb, 256, 0, stream>>>(hf, offs, centry, dis, b1, y1, stats1, n);
    // layer 2 — V0n replica (noise check)
    gemm_kernel<HD, true><<<nhb, 256, 0, stream>>>(y1, W2, stats1, g1, be1, dis, hf, stats2, n);
    aggV0n_kernel<<<aggb, 256, 0, stream>>>(hf, offs, centry, dis, b2, y2, stats2, n);
    // layer 3 — V4n (contiguous-split, 4 consecutive preloads)
    gemm_kernel<HD, true><<<nhb, 256, 0, stream>>>(y2, W3, stats2, g2, be2, dis, hf, stats3, n);
    aggV4n_kernel<<<aggb, 256, 0, stream>>>(hf, offs, centry, dis, b3, y3, stats3, n);

    final_kernel<<<nb, 256, 0, stream>>>(y1, y2, y3, stats1, stats2, stats3,
                                         g1, be1, g2, be2, g3, be3, Wl, bl, (float*)d_out, n);
}

// Round 9
// 457.701 us; speedup vs baseline: 1.2621x; 1.0468x over previous
//
#include <hip/hip_runtime.h>

typedef unsigned int uint;
typedef unsigned short ushort;
typedef unsigned long long ull;

#define F_IN 64
#define HD 32
#define NCLS 2
#define BN_EPS 1e-5f
#define SCHUNK 1024
#define NPW 16
#define FIX_SCALE 1073741824.0f            // 2^30
#define FIX_INV   9.313225746154785e-10f   // 2^-30
#define MASK40 ((1ULL << 40) - 1)

__device__ __forceinline__ ull ld64(const int2* p) {
    return *reinterpret_cast<const ull*>(p);
}

// ---------- fused histogram: u64 atomic = count(hi24)+fixedpoint deg(lo40); epos = rank ----------
__global__ void hist64_kernel(const int* __restrict__ ei, const float* __restrict__ w,
                              ull* __restrict__ packed, ushort* __restrict__ epos, int E) {
    int e = blockIdx.x * blockDim.x + threadIdx.x;
    if (e >= E) return;
    int c = ei[E + e];
    ull fx = (ull)(w[e] * FIX_SCALE + 0.5f);
    ull old = atomicAdd(&packed[c], (1ULL << 40) | fx);
    epos[e] = (ushort)(old >> 40);
}

// ---------- scan phase A: per-chunk counts-sums; fused dis = rsqrt(deg+1) ----------
__global__ void scanA_kernel(const ull* __restrict__ packed,
                             int* __restrict__ partial, float* __restrict__ dis, int n) {
    __shared__ int red[256];
    int base = blockIdx.x * SCHUNK;
    int tid = threadIdx.x;
    int s = 0;
    for (int i = tid; i < SCHUNK; i += 256) {
        int idx = base + i;
        if (idx < n) {
            ull p = packed[idx];
            s += (int)(p >> 40);
            float deg = (float)(p & MASK40) * FIX_INV;
            dis[idx] = rsqrtf(deg + 1.0f);   // self-loop weight 1; arg >= 1
        }
    }
    red[tid] = s;
    __syncthreads();
    for (int off = 128; off > 0; off >>= 1) {
        if (tid < off) red[tid] += red[tid + off];
        __syncthreads();
    }
    if (tid == 0) partial[blockIdx.x] = red[0];
}

// ---------- scan phase B ----------
__global__ void scanB_kernel(int* __restrict__ partial, int nb, int* __restrict__ offs_n) {
    __shared__ int lds[256];
    int tid = threadIdx.x;
    int v = (tid < nb) ? partial[tid] : 0;
    lds[tid] = v;
    __syncthreads();
    for (int off = 1; off < 256; off <<= 1) {
        int t = (tid >= off) ? lds[tid - off] : 0;
        __syncthreads();
        lds[tid] += t;
        __syncthreads();
    }
    if (tid < nb) partial[tid] = lds[tid] - v;
    if (tid == nb - 1) *offs_n = lds[tid];
}

// ---------- scan phase C ----------
__global__ void scanC_kernel(const ull* __restrict__ packed, const int* __restrict__ partial,
                             int* __restrict__ offs, int n) {
    __shared__ int lds[256];
    int tid = threadIdx.x;
    int i0 = blockIdx.x * SCHUNK + tid * 4;
    int c0 = 0, c1 = 0, c2 = 0, c3 = 0;
    if (i0 + 0 < n) c0 = (int)(packed[i0 + 0] >> 40);
    if (i0 + 1 < n) c1 = (int)(packed[i0 + 1] >> 40);
    if (i0 + 2 < n) c2 = (int)(packed[i0 + 2] >> 40);
    if (i0 + 3 < n) c3 = (int)(packed[i0 + 3] >> 40);
    int tsum = c0 + c1 + c2 + c3;
    lds[tid] = tsum;
    __syncthreads();
    for (int off = 1; off < 256; off <<= 1) {
        int t = (tid >= off) ? lds[tid - off] : 0;
        __syncthreads();
        lds[tid] += t;
        __syncthreads();
    }
    int run = partial[blockIdx.x] + lds[tid] - tsum;
    int o0 = run, o1 = o0 + c0, o2 = o1 + c1, o3 = o2 + c2;
    if (i0 + 0 < n) offs[i0 + 0] = o0;
    if (i0 + 1 < n) offs[i0 + 1] = o1;
    if (i0 + 2 < n) offs[i0 + 2] = o2;
    if (i0 + 3 < n) offs[i0 + 3] = o3;
}

// ---------- fill CSR (atomic-free, no dis reads): centry[pos] = (row, raw_w) ----------
__global__ void fill_kernel(const int* __restrict__ ei, const float* __restrict__ w,
                            const int* __restrict__ offs, const ushort* __restrict__ epos,
                            int2* __restrict__ centry, int E) {
    int e = blockIdx.x * blockDim.x + threadIdx.x;
    if (e >= E) return;
    int r = ei[e], c = ei[E + e];
    int pos = offs[c] + (int)epos[e];
    centry[pos] = make_int2(r, __float_as_int(w[e]));
}

// ---------- small GEMM: Hf[N,32] = (bn?(X) @ W) * dis[node]  (dis folded in) ----------
template <int FIN, bool BN>
__global__ void gemm_kernel(const float* __restrict__ X, const float* __restrict__ W,
                            const float* __restrict__ statsPrev, const float* __restrict__ g,
                            const float* __restrict__ be, const float* __restrict__ dis,
                            float* __restrict__ Hf, float* __restrict__ statsCur, int n) {
    __shared__ float Wl[FIN * HD];
    __shared__ float scl[64];
    for (int i = threadIdx.x; i < FIN * HD; i += blockDim.x) Wl[i] = W[i];
    if (BN && threadIdx.x < 32) {
        int h = threadIdx.x;
        float invn = 1.0f / (float)n;
        float mean = statsPrev[h] * invn;
        float var = statsPrev[32 + h] * invn - mean * mean;   // biased
        float sca = rsqrtf(var + BN_EPS) * g[h];
        scl[h] = sca;
        scl[32 + h] = be[h] - mean * sca;
    }
    if (blockIdx.x == 0 && threadIdx.x < 64) statsCur[threadIdx.x] = 0.0f;
    __syncthreads();
    int idx = blockIdx.x * blockDim.x + threadIdx.x;
    if (idx >= n * HD) return;
    int node = idx >> 5, h = idx & 31;
    const float4* xr4 = reinterpret_cast<const float4*>(X + (size_t)node * FIN);
    float acc = 0.0f;
#pragma unroll
    for (int q = 0; q < FIN / 4; q++) {
        float4 v4 = xr4[q];
        float vs[4] = {v4.x, v4.y, v4.z, v4.w};
#pragma unroll
        for (int j = 0; j < 4; j++) {
            int k = q * 4 + j;
            float v = vs[j];
            if (BN) v = v * scl[k] + scl[32 + k];
            acc += v * Wl[k * HD + h];
        }
    }
    Hf[idx] = acc * dis[node];               // hlin' = h * dis
}

// y[c] = relu(bias + dis[c]*(hlin'[c] + sum_e w_e*hlin'[row_e]))   [dis factored out]
// ====== V4n: contiguous-split halves, 4 consecutive ld64 preload -> 4 indep gathers ======
__global__ void aggV4n_kernel(const float* __restrict__ hf, const int* __restrict__ offs,
                              const int2* __restrict__ centry, const float* __restrict__ dis,
                              const float* __restrict__ bias, float* __restrict__ y,
                              float* __restrict__ stats, int n) {
    int wave = threadIdx.x >> 6, lane = threadIdx.x & 63, sub = lane >> 5, h = lane & 31;
    float bv = bias[h];
    float lsum = 0.f, lsq = 0.f;
    int base = (blockIdx.x * 4 + wave) * NPW;
    for (int t = 0; t < NPW; t++) {
        int node = base + t;
        if (node >= n) break;
        int s = offs[node], e2 = offs[node + 1];
        int len = e2 - s;
        int half = (len + 1) >> 1;
        int j    = sub ? (s + half) : s;          // contiguous halves
        int jend = sub ? e2 : (s + half);
        float dd = dis[node];
        float a0 = 0.f, a1 = 0.f, a2 = 0.f, a3 = 0.f;
        if (sub == 0) a0 = hf[(size_t)node * HD + h];       // self-loop
        for (; j + 3 < jend; j += 4) {
            ull p0 = ld64(centry + j);
            ull p1 = ld64(centry + j + 1);
            ull p2 = ld64(centry + j + 2);
            ull p3 = ld64(centry + j + 3);
            a0 += hf[(size_t)(uint)p0 * HD + h] * __uint_as_float((uint)(p0 >> 32));
            a1 += hf[(size_t)(uint)p1 * HD + h] * __uint_as_float((uint)(p1 >> 32));
            a2 += hf[(size_t)(uint)p2 * HD + h] * __uint_as_float((uint)(p2 >> 32));
            a3 += hf[(size_t)(uint)p3 * HD + h] * __uint_as_float((uint)(p3 >> 32));
        }
        for (; j < jend; j++) {
            ull p0 = ld64(centry + j);
            a0 += hf[(size_t)(uint)p0 * HD + h] * __uint_as_float((uint)(p0 >> 32));
        }
        a0 += a1 + a2 + a3;
        a0 += __shfl_xor(a0, 32, 64);
        float yv = fmaxf(fmaf(a0, dd, bv), 0.f);
        if (sub == 0) {
            y[(size_t)node * HD + h] = yv;
            lsum += yv; lsq += yv * yv;
        }
    }
    __shared__ float ls[4][32], lq[4][32];
    if (sub == 0) { ls[wave][h] = lsum; lq[wave][h] = lsq; }
    __syncthreads();
    if (threadIdx.x < 32) {
        float a = ls[0][threadIdx.x] + ls[1][threadIdx.x] + ls[2][threadIdx.x] + ls[3][threadIdx.x];
        float b = lq[0][threadIdx.x] + lq[1][threadIdx.x] + lq[2][threadIdx.x] + lq[3][threadIdx.x];
        atomicAdd(&stats[threadIdx.x], a);
        atomicAdd(&stats[32 + threadIdx.x], b);
    }
}

// ---------- final linear: bn(y1..3) concat [N,96] @ [96,2] + bl; BN inline ----------
__global__ void final_kernel(const float* __restrict__ y1, const float* __restrict__ y2,
                             const float* __restrict__ y3,
                             const float* __restrict__ s1, const float* __restrict__ s2,
                             const float* __restrict__ s3,
                             const float* __restrict__ g1, const float* __restrict__ be1,
                             const float* __restrict__ g2, const float* __restrict__ be2,
                             const float* __restrict__ g3, const float* __restrict__ be3,
                             const float* __restrict__ Wl, const float* __restrict__ bl,
                             float* __restrict__ out, int n) {
    __shared__ float Ws[96 * NCLS];
    __shared__ float scs[3][64];
    __shared__ float bs[NCLS];
    for (int i = threadIdx.x; i < 96 * NCLS; i += blockDim.x) Ws[i] = Wl[i];
    if (threadIdx.x < 96) {
        int L = threadIdx.x >> 5, h = threadIdx.x & 31;
        const float* st = (L == 0) ? s1 : (L == 1) ? s2 : s3;
        const float* gg = (L == 0) ? g1 : (L == 1) ? g2 : g3;
        const float* bb = (L == 0) ? be1 : (L == 1) ? be2 : be3;
        float invn = 1.0f / (float)n;
        float mean = st[h] * invn;
        float var = st[32 + h] * invn - mean * mean;
        float sca = rsqrtf(var + BN_EPS) * gg[h];
        scs[L][h] = sca;
        scs[L][32 + h] = bb[h] - mean * sca;
    }
    if (threadIdx.x < NCLS) bs[threadIdx.x] = bl[threadIdx.x];
    __syncthreads();
    int i = blockIdx.x * blockDim.x + threadIdx.x;
    if (i >= n) return;
    float a0 = bs[0], a1 = bs[1];
    const float* ys[3] = {y1 + (size_t)i * HD, y2 + (size_t)i * HD, y3 + (size_t)i * HD};
#pragma unroll
    for (int L = 0; L < 3; L++) {
        const float4* r4 = reinterpret_cast<const float4*>(ys[L]);
#pragma unroll
        for (int q = 0; q < HD / 4; q++) {
            float4 v4 = r4[q];
            float vs[4] = {v4.x, v4.y, v4.z, v4.w};
#pragma unroll
            for (int j = 0; j < 4; j++) {
                int h = q * 4 + j;
                float v = vs[j] * scs[L][h] + scs[L][32 + h];
                a0 += v * Ws[(L * 32 + h) * 2];
                a1 += v * Ws[(L * 32 + h) * 2 + 1];
            }
        }
    }
    out[(size_t)i * 2] = a0;
    out[(size_t)i * 2 + 1] = a1;
}

extern "C" void kernel_launch(void* const* d_in, const int* in_sizes, int n_in,
                              void* d_out, int out_size, void* d_ws, size_t ws_size,
                              hipStream_t stream) {
    const float* x  = (const float*)d_in[0];
    const int*   ei = (const int*)d_in[1];
    const float* ew = (const float*)d_in[2];
    const float* W1 = (const float*)d_in[3];  const float* b1  = (const float*)d_in[4];
    const float* g1 = (const float*)d_in[5];  const float* be1 = (const float*)d_in[6];
    const float* W2 = (const float*)d_in[7];  const float* b2  = (const float*)d_in[8];
    const float* g2 = (const float*)d_in[9];  const float* be2 = (const float*)d_in[10];
    const float* W3 = (const float*)d_in[11]; const float* b3  = (const float*)d_in[12];
    const float* g3 = (const float*)d_in[13]; const float* be3 = (const float*)d_in[14];
    const float* Wl = (const float*)d_in[15]; const float* bl  = (const float*)d_in[16];

    int n = in_sizes[0] / F_IN;
    int E = in_sizes[1] / 2;

    char* ws = (char*)d_ws;
    auto alloc = [&](size_t bytes) -> char* {
        char* p = ws;
        ws += (bytes + 255) / 256 * 256;
        return p;
    };
    ull*    packed = (ull*)alloc((size_t)n * 8);
    float*  dis    = (float*)alloc((size_t)n * 4);
    int*    offs   = (int*)alloc((size_t)(n + 1) * 4);
    int*    partial= (int*)alloc(256 * 4);
    ushort* epos   = (ushort*)alloc((size_t)E * 2);
    int2*   centry = (int2*)alloc((size_t)E * 8);
    float*  hf     = (float*)alloc((size_t)n * HD * 4);
    float*  y1     = (float*)alloc((size_t)n * HD * 4);
    float*  y2     = (float*)alloc((size_t)n * HD * 4);
    float*  y3     = (float*)alloc((size_t)n * HD * 4);
    float*  stats1 = (float*)alloc(64 * 4);
    float*  stats2 = (float*)alloc(64 * 4);
    float*  stats3 = (float*)alloc(64 * 4);

    hipMemsetAsync(packed, 0, (size_t)n * 8, stream);

    int eb  = (E + 255) / 256;
    int nb  = (n + 255) / 256;
    int nhb = (n * HD + 255) / 256;
    int scb = (n + SCHUNK - 1) / SCHUNK;            // 98 for n=100000 (<=256 required)
    int aggb = (n + 4 * NPW - 1) / (4 * NPW);

    hist64_kernel<<<eb, 256, 0, stream>>>(ei, ew, packed, epos, E);
    scanA_kernel<<<scb, 256, 0, stream>>>(packed, partial, dis, n);
    scanB_kernel<<<1, 256, 0, stream>>>(partial, scb, offs + n);
    scanC_kernel<<<scb, 256, 0, stream>>>(packed, partial, offs, n);
    fill_kernel<<<eb, 256, 0, stream>>>(ei, ew, offs, epos, centry, E);

    // layer 1 — V4n
    gemm_kernel<F_IN, false><<<nhb, 256, 0, stream>>>(x, W1, nullptr, nullptr, nullptr, dis, hf, stats1, n);
    aggV4n_kernel<<<aggb, 256, 0, stream>>>(hf, offs, centry, dis, b1, y1, stats1, n);
    // layer 2 — V4n
    gemm_kernel<HD, true><<<nhb, 256, 0, stream>>>(y1, W2, stats1, g1, be1, dis, hf, stats2, n);
    aggV4n_kernel<<<aggb, 256, 0, stream>>>(hf, offs, centry, dis, b2, y2, stats2, n);
    // layer 3 — V4n
    gemm_kernel<HD, true><<<nhb, 256, 0, stream>>>(y2, W3, stats2, g2, be2, dis, hf, stats3, n);
    aggV4n_kernel<<<aggb, 256, 0, stream>>>(hf, offs, centry, dis, b3, y3, stats3, n);

    final_kernel<<<nb, 256, 0, stream>>>(y1, y2, y3, stats1, stats2, stats3,
                                         g1, be1, g2, be2, g3, be3, Wl, bl, (float*)d_out, n);
}

// Round 10
// 455.553 us; speedup vs baseline: 1.2681x; 1.0047x over previous
//
#include <hip/hip_runtime.h>

typedef unsigned int uint;
typedef unsigned short ushort;
typedef unsigned long long ull;

#define F_IN 64
#define HD 32
#define NCLS 2
#define BN_EPS 1e-5f
#define SCHUNK 1024
#define NPW 16
#define FIX_SCALE 1073741824.0f            // 2^30
#define FIX_INV   9.313225746154785e-10f   // 2^-30
#define MASK40 ((1ULL << 40) - 1)

__device__ __forceinline__ ull ld64(const int2* p) {
    return *reinterpret_cast<const ull*>(p);
}
__device__ __forceinline__ ushort f2bf(float f) {
    uint u = __float_as_uint(f);
    u = (u + 0x7FFFu + ((u >> 16) & 1u)) >> 16;   // RNE
    return (ushort)u;
}
__device__ __forceinline__ float bf2f(ushort b) {
    return __uint_as_float((uint)b << 16);
}

// ---------- fused histogram: u64 atomic = count(hi24)+fixedpoint deg(lo40); epos = rank ----------
__global__ void hist64_kernel(const int* __restrict__ ei, const float* __restrict__ w,
                              ull* __restrict__ packed, ushort* __restrict__ epos, int E) {
    int e = blockIdx.x * blockDim.x + threadIdx.x;
    if (e >= E) return;
    int c = ei[E + e];
    ull fx = (ull)(w[e] * FIX_SCALE + 0.5f);
    ull old = atomicAdd(&packed[c], (1ULL << 40) | fx);
    epos[e] = (ushort)(old >> 40);
}

// ---------- scan phase A: per-chunk counts-sums; fused dis = rsqrt(deg+1) ----------
__global__ void scanA_kernel(const ull* __restrict__ packed,
                             int* __restrict__ partial, float* __restrict__ dis, int n) {
    __shared__ int red[256];
    int base = blockIdx.x * SCHUNK;
    int tid = threadIdx.x;
    int s = 0;
    for (int i = tid; i < SCHUNK; i += 256) {
        int idx = base + i;
        if (idx < n) {
            ull p = packed[idx];
            s += (int)(p >> 40);
            float deg = (float)(p & MASK40) * FIX_INV;
            dis[idx] = rsqrtf(deg + 1.0f);   // self-loop weight 1; arg >= 1
        }
    }
    red[tid] = s;
    __syncthreads();
    for (int off = 128; off > 0; off >>= 1) {
        if (tid < off) red[tid] += red[tid + off];
        __syncthreads();
    }
    if (tid == 0) partial[blockIdx.x] = red[0];
}

// ---------- scan phase B ----------
__global__ void scanB_kernel(int* __restrict__ partial, int nb, int* __restrict__ offs_n) {
    __shared__ int lds[256];
    int tid = threadIdx.x;
    int v = (tid < nb) ? partial[tid] : 0;
    lds[tid] = v;
    __syncthreads();
    for (int off = 1; off < 256; off <<= 1) {
        int t = (tid >= off) ? lds[tid - off] : 0;
        __syncthreads();
        lds[tid] += t;
        __syncthreads();
    }
    if (tid < nb) partial[tid] = lds[tid] - v;
    if (tid == nb - 1) *offs_n = lds[tid];
}

// ---------- scan phase C ----------
__global__ void scanC_kernel(const ull* __restrict__ packed, const int* __restrict__ partial,
                             int* __restrict__ offs, int n) {
    __shared__ int lds[256];
    int tid = threadIdx.x;
    int i0 = blockIdx.x * SCHUNK + tid * 4;
    int c0 = 0, c1 = 0, c2 = 0, c3 = 0;
    if (i0 + 0 < n) c0 = (int)(packed[i0 + 0] >> 40);
    if (i0 + 1 < n) c1 = (int)(packed[i0 + 1] >> 40);
    if (i0 + 2 < n) c2 = (int)(packed[i0 + 2] >> 40);
    if (i0 + 3 < n) c3 = (int)(packed[i0 + 3] >> 40);
    int tsum = c0 + c1 + c2 + c3;
    lds[tid] = tsum;
    __syncthreads();
    for (int off = 1; off < 256; off <<= 1) {
        int t = (tid >= off) ? lds[tid - off] : 0;
        __syncthreads();
        lds[tid] += t;
        __syncthreads();
    }
    int run = partial[blockIdx.x] + lds[tid] - tsum;
    int o0 = run, o1 = o0 + c0, o2 = o1 + c1, o3 = o2 + c2;
    if (i0 + 0 < n) offs[i0 + 0] = o0;
    if (i0 + 1 < n) offs[i0 + 1] = o1;
    if (i0 + 2 < n) offs[i0 + 2] = o2;
    if (i0 + 3 < n) offs[i0 + 3] = o3;
}

// ---------- fill CSR (atomic-free, no dis reads): centry[pos] = (row, raw_w) ----------
__global__ void fill_kernel(const int* __restrict__ ei, const float* __restrict__ w,
                            const int* __restrict__ offs, const ushort* __restrict__ epos,
                            int2* __restrict__ centry, int E) {
    int e = blockIdx.x * blockDim.x + threadIdx.x;
    if (e >= E) return;
    int r = ei[e], c = ei[E + e];
    int pos = offs[c] + (int)epos[e];
    centry[pos] = make_int2(r, __float_as_int(w[e]));
}

// ---------- small GEMM: Hb[N,32](bf16) = ((bn?(X) @ W) * dis[node]) ----------
template <int FIN, bool BN>
__global__ void gemm_kernel(const float* __restrict__ X, const float* __restrict__ W,
                            const float* __restrict__ statsPrev, const float* __restrict__ g,
                            const float* __restrict__ be, const float* __restrict__ dis,
                            ushort* __restrict__ Hb, float* __restrict__ statsCur, int n) {
    __shared__ float Wl[FIN * HD];
    __shared__ float scl[64];
    for (int i = threadIdx.x; i < FIN * HD; i += blockDim.x) Wl[i] = W[i];
    if (BN && threadIdx.x < 32) {
        int h = threadIdx.x;
        float invn = 1.0f / (float)n;
        float mean = statsPrev[h] * invn;
        float var = statsPrev[32 + h] * invn - mean * mean;   // biased
        float sca = rsqrtf(var + BN_EPS) * g[h];
        scl[h] = sca;
        scl[32 + h] = be[h] - mean * sca;
    }
    if (blockIdx.x == 0 && threadIdx.x < 64) statsCur[threadIdx.x] = 0.0f;
    __syncthreads();
    int idx = blockIdx.x * blockDim.x + threadIdx.x;
    if (idx >= n * HD) return;
    int node = idx >> 5, h = idx & 31;
    const float4* xr4 = reinterpret_cast<const float4*>(X + (size_t)node * FIN);
    float acc = 0.0f;
#pragma unroll
    for (int q = 0; q < FIN / 4; q++) {
        float4 v4 = xr4[q];
        float vs[4] = {v4.x, v4.y, v4.z, v4.w};
#pragma unroll
        for (int j = 0; j < 4; j++) {
            int k = q * 4 + j;
            float v = vs[j];
            if (BN) v = v * scl[k] + scl[32 + k];
            acc += v * Wl[k * HD + h];
        }
    }
    Hb[idx] = f2bf(acc * dis[node]);         // hlin' = h * dis, bf16 row (64 B)
}

// y[c] = relu(bias + dis[c]*(hlin'[c] + sum_e w_e*hlin'[row_e]))   [dis factored out]
// ====== V4n-bf16: contiguous halves, 4 consecutive ld64 preload -> 4 indep bf16 gathers ======
__global__ void aggV4n_kernel(const ushort* __restrict__ hb, const int* __restrict__ offs,
                              const int2* __restrict__ centry, const float* __restrict__ dis,
                              const float* __restrict__ bias, float* __restrict__ y,
                              float* __restrict__ stats, int n) {
    int wave = threadIdx.x >> 6, lane = threadIdx.x & 63, sub = lane >> 5, h = lane & 31;
    float bv = bias[h];
    float lsum = 0.f, lsq = 0.f;
    int base = (blockIdx.x * 4 + wave) * NPW;
    for (int t = 0; t < NPW; t++) {
        int node = base + t;
        if (node >= n) break;
        int s = offs[node], e2 = offs[node + 1];
        int len = e2 - s;
        int half = (len + 1) >> 1;
        int j    = sub ? (s + half) : s;          // contiguous halves
        int jend = sub ? e2 : (s + half);
        float dd = dis[node];
        float a0 = 0.f, a1 = 0.f, a2 = 0.f, a3 = 0.f;
        if (sub == 0) a0 = bf2f(hb[(size_t)node * HD + h]);   // self-loop
        for (; j + 3 < jend; j += 4) {
            ull p0 = ld64(centry + j);
            ull p1 = ld64(centry + j + 1);
            ull p2 = ld64(centry + j + 2);
            ull p3 = ld64(centry + j + 3);
            a0 += bf2f(hb[(size_t)(uint)p0 * HD + h]) * __uint_as_float((uint)(p0 >> 32));
            a1 += bf2f(hb[(size_t)(uint)p1 * HD + h]) * __uint_as_float((uint)(p1 >> 32));
            a2 += bf2f(hb[(size_t)(uint)p2 * HD + h]) * __uint_as_float((uint)(p2 >> 32));
            a3 += bf2f(hb[(size_t)(uint)p3 * HD + h]) * __uint_as_float((uint)(p3 >> 32));
        }
        for (; j < jend; j++) {
            ull p0 = ld64(centry + j);
            a0 += bf2f(hb[(size_t)(uint)p0 * HD + h]) * __uint_as_float((uint)(p0 >> 32));
        }
        a0 += a1 + a2 + a3;
        a0 += __shfl_xor(a0, 32, 64);
        float yv = fmaxf(fmaf(a0, dd, bv), 0.f);
        if (sub == 0) {
            y[(size_t)node * HD + h] = yv;
            lsum += yv; lsq += yv * yv;
        }
    }
    __shared__ float ls[4][32], lq[4][32];
    if (sub == 0) { ls[wave][h] = lsum; lq[wave][h] = lsq; }
    __syncthreads();
    if (threadIdx.x < 32) {
        float a = ls[0][threadIdx.x] + ls[1][threadIdx.x] + ls[2][threadIdx.x] + ls[3][threadIdx.x];
        float b = lq[0][threadIdx.x] + lq[1][threadIdx.x] + lq[2][threadIdx.x] + lq[3][threadIdx.x];
        atomicAdd(&stats[threadIdx.x], a);
        atomicAdd(&stats[32 + threadIdx.x], b);
    }
}

// ---------- final linear: bn(y1..3) concat [N,96] @ [96,2] + bl; BN inline ----------
__global__ void final_kernel(const float* __restrict__ y1, const float* __restrict__ y2,
                             const float* __restrict__ y3,
                             const float* __restrict__ s1, const float* __restrict__ s2,
                             const float* __restrict__ s3,
                             const float* __restrict__ g1, const float* __restrict__ be1,
                             const float* __restrict__ g2, const float* __restrict__ be2,
                             const float* __restrict__ g3, const float* __restrict__ be3,
                             const float* __restrict__ Wl, const float* __restrict__ bl,
                             float* __restrict__ out, int n) {
    __shared__ float Ws[96 * NCLS];
    __shared__ float scs[3][64];
    __shared__ float bs[NCLS];
    for (int i = threadIdx.x; i < 96 * NCLS; i += blockDim.x) Ws[i] = Wl[i];
    if (threadIdx.x < 96) {
        int L = threadIdx.x >> 5, h = threadIdx.x & 31;
        const float* st = (L == 0) ? s1 : (L == 1) ? s2 : s3;
        const float* gg = (L == 0) ? g1 : (L == 1) ? g2 : g3;
        const float* bb = (L == 0) ? be1 : (L == 1) ? be2 : be3;
        float invn = 1.0f / (float)n;
        float mean = st[h] * invn;
        float var = st[32 + h] * invn - mean * mean;
        float sca = rsqrtf(var + BN_EPS) * gg[h];
        scs[L][h] = sca;
        scs[L][32 + h] = bb[h] - mean * sca;
    }
    if (threadIdx.x < NCLS) bs[threadIdx.x] = bl[threadIdx.x];
    __syncthreads();
    int i = blockIdx.x * blockDim.x + threadIdx.x;
    if (i >= n) return;
    float a0 = bs[0], a1 = bs[1];
    const float* ys[3] = {y1 + (size_t)i * HD, y2 + (size_t)i * HD, y3 + (size_t)i * HD};
#pragma unroll
    for (int L = 0; L < 3; L++) {
        const float4* r4 = reinterpret_cast<const float4*>(ys[L]);
#pragma unroll
        for (int q = 0; q < HD / 4; q++) {
            float4 v4 = r4[q];
            float vs[4] = {v4.x, v4.y, v4.z, v4.w};
#pragma unroll
            for (int j = 0; j < 4; j++) {
                int h = q * 4 + j;
                float v = vs[j] * scs[L][h] + scs[L][32 + h];
                a0 += v * Ws[(L * 32 + h) * 2];
                a1 += v * Ws[(L * 32 + h) * 2 + 1];
            }
        }
    }
    out[(size_t)i * 2] = a0;
    out[(size_t)i * 2 + 1] = a1;
}

extern "C" void kernel_launch(void* const* d_in, const int* in_sizes, int n_in,
                              void* d_out, int out_size, void* d_ws, size_t ws_size,
                              hipStream_t stream) {
    const float* x  = (const float*)d_in[0];
    const int*   ei = (const int*)d_in[1];
    const float* ew = (const float*)d_in[2];
    const float* W1 = (const float*)d_in[3];  const float* b1  = (const float*)d_in[4];
    const float* g1 = (const float*)d_in[5];  const float* be1 = (const float*)d_in[6];
    const float* W2 = (const float*)d_in[7];  const float* b2  = (const float*)d_in[8];
    const float* g2 = (const float*)d_in[9];  const float* be2 = (const float*)d_in[10];
    const float* W3 = (const float*)d_in[11]; const float* b3  = (const float*)d_in[12];
    const float* g3 = (const float*)d_in[13]; const float* be3 = (const float*)d_in[14];
    const float* Wl = (const float*)d_in[15]; const float* bl  = (const float*)d_in[16];

    int n = in_sizes[0] / F_IN;
    int E = in_sizes[1] / 2;

    char* ws = (char*)d_ws;
    auto alloc = [&](size_t bytes) -> char* {
        char* p = ws;
        ws += (bytes + 255) / 256 * 256;
        return p;
    };
    ull*    packed = (ull*)alloc((size_t)n * 8);
    float*  dis    = (float*)alloc((size_t)n * 4);
    int*    offs   = (int*)alloc((size_t)(n + 1) * 4);
    int*    partial= (int*)alloc(256 * 4);
    ushort* epos   = (ushort*)alloc((size_t)E * 2);
    int2*   centry = (int2*)alloc((size_t)E * 8);
    ushort* hb     = (ushort*)alloc((size_t)n * HD * 2);
    float*  y1     = (float*)alloc((size_t)n * HD * 4);
    float*  y2     = (float*)alloc((size_t)n * HD * 4);
    float*  y3     = (float*)alloc((size_t)n * HD * 4);
    float*  stats1 = (float*)alloc(64 * 4);
    float*  stats2 = (float*)alloc(64 * 4);
    float*  stats3 = (float*)alloc(64 * 4);

    hipMemsetAsync(packed, 0, (size_t)n * 8, stream);

    int eb  = (E + 255) / 256;
    int nb  = (n + 255) / 256;
    int nhb = (n * HD + 255) / 256;
    int scb = (n + SCHUNK - 1) / SCHUNK;            // 98 for n=100000 (<=256 required)
    int aggb = (n + 4 * NPW - 1) / (4 * NPW);

    hist64_kernel<<<eb, 256, 0, stream>>>(ei, ew, packed, epos, E);
    scanA_kernel<<<scb, 256, 0, stream>>>(packed, partial, dis, n);
    scanB_kernel<<<1, 256, 0, stream>>>(partial, scb, offs + n);
    scanC_kernel<<<scb, 256, 0, stream>>>(packed, partial, offs, n);
    fill_kernel<<<eb, 256, 0, stream>>>(ei, ew, offs, epos, centry, E);

    // layer 1 — V4n bf16
    gemm_kernel<F_IN, false><<<nhb, 256, 0, stream>>>(x, W1, nullptr, nullptr, nullptr, dis, hb, stats1, n);
    aggV4n_kernel<<<aggb, 256, 0, stream>>>(hb, offs, centry, dis, b1, y1, stats1, n);
    // layer 2 — V4n bf16
    gemm_kernel<HD, true><<<nhb, 256, 0, stream>>>(y1, W2, stats1, g1, be1, dis, hb, stats2, n);
    aggV4n_kernel<<<aggb, 256, 0, stream>>>(hb, offs, centry, dis, b2, y2, stats2, n);
    // layer 3 — V4n bf16
    gemm_kernel<HD, true><<<nhb, 256, 0, stream>>>(y2, W3, stats2, g2, be2, dis, hb, stats3, n);
    aggV4n_kernel<<<aggb, 256, 0, stream>>>(hb, offs, centry, dis, b3, y3, stats3, n);

    final_kernel<<<nb, 256, 0, stream>>>(y1, y2, y3, stats1, stats2, stats3,
                                         g1, be1, g2, be2, g3, be3, Wl, bl, (float*)d_out, n);
}